// Round 1
// baseline (352.725 us; speedup 1.0000x reference)
//
#include <hip/hip_runtime.h>

#define NSL 8
#define DIN 384
#define DS 128
#define BATCH 32
#define NPOS 4096
#define LN_EPS 1e-5f
#define THRESH 0.9f
#define NCH 32          // feature chunks per batch (128 rows each)

// attn = 0.125 exactly (softmax of identical logits across slots);
// sum over N = 512.0 exactly; 512.0f + 1e-8f == 512.0f; 0.125/512 = 2^-12
#define ATTN_NORM_C 0.000244140625f

// ---------------- K1: streaming  Σ_rows rstd·(x−μ)  (per column) + attn fill ----------------
// BYTE-IDENTICAL to prior round (at its ~32 us HBM roofline).
__global__ __launch_bounds__(256) void colsum_kernel(const float* __restrict__ feat,
                                                     float* __restrict__ G_part,   // [32][NCH][384]
                                                     float* __restrict__ out_attn) {
    __shared__ float S_lds[16][384];   // 24 KB
    int t = threadIdx.x, w = t >> 6, lane = t & 63;
    int group = lane >> 4, gl = lane & 15;
    int b = blockIdx.y, ch = blockIdx.x;
    int row0 = ch * 128 + w * 32 + group;
    const float4* fbase = (const float4*)(feat + ((size_t)b * NPOS + row0) * DIN);

    float4 acc[6];
#pragma unroll
    for (int s = 0; s < 6; s++) { acc[s].x = 0.f; acc[s].y = 0.f; acc[s].z = 0.f; acc[s].w = 0.f; }

    float4 xA[6], xB[6];
#pragma unroll
    for (int s = 0; s < 6; s++) xA[s] = fbase[s * 16 + gl];

#pragma unroll
    for (int j = 0; j < 8; j++) {
        if (j < 7) {
            const float4* rp = fbase + (size_t)(j + 1) * 384;
#pragma unroll
            for (int s = 0; s < 6; s++) xB[s] = rp[s * 16 + gl];
        }
        float sm = 0.f, sq = 0.f;
#pragma unroll
        for (int s = 0; s < 6; s++) {
            sm += xA[s].x + xA[s].y + xA[s].z + xA[s].w;
            sq += xA[s].x * xA[s].x + xA[s].y * xA[s].y + xA[s].z * xA[s].z + xA[s].w * xA[s].w;
        }
#pragma unroll
        for (int m = 1; m < 16; m <<= 1) {
            sm += __shfl_xor(sm, m, 64);
            sq += __shfl_xor(sq, m, 64);
        }
        float mean = sm * (1.f / 384.f);
        float var = sq * (1.f / 384.f) - mean * mean;
        float rstd = rsqrtf(var + LN_EPS);
#pragma unroll
        for (int s = 0; s < 6; s++) {
            acc[s].x += (xA[s].x - mean) * rstd;
            acc[s].y += (xA[s].y - mean) * rstd;
            acc[s].z += (xA[s].z - mean) * rstd;
            acc[s].w += (xA[s].w - mean) * rstd;
        }
#pragma unroll
        for (int s = 0; s < 6; s++) xA[s] = xB[s];
    }
    int gr = w * 4 + group;
#pragma unroll
    for (int s = 0; s < 6; s++)
        *(float4*)&S_lds[gr][s * 64 + gl * 4] = acc[s];
    __syncthreads();
    for (int q = t; q < 384; q += 256) {
        float v = 0.f;
#pragma unroll
        for (int r = 0; r < 16; r++) v += S_lds[r][q];
        G_part[((size_t)b * NCH + ch) * 384 + q] = v;
    }
    int s8 = t >> 5, p = t & 31;
    size_t ao = ((size_t)(b * 8 + s8)) * NPOS + ch * 128;
    out_attn[ao + p] = 0.125f;
    out_attn[ao + 32 + p] = 0.125f;
    out_attn[ao + 64 + p] = 0.125f;
    out_attn[ao + 96 + p] = 0.125f;
}

// ---------------- K2: 1024-thread block, 2-D (output x k-chunk) split matvecs ----------------
// One block per batch; every matvec phase uses all 16 waves; fixed-order LDS
// combines keep results deterministic and identical across batches/slots.
// This round: W_ih/W_hh read DIRECTLY (row j = 128 consecutive floats -> per-thread
// float4 runs), eliminating the prep transpose kernel and halving the serial
// load-chunk chain in phases C/D (2 chunks of 8 float4 vs 4 chunks of 16 scalars).
// Accumulation order over k is exactly unchanged.
__global__ __launch_bounds__(1024) void slots_kernel(
    const float* __restrict__ G_part,
    const float* __restrict__ g_in, const float* __restrict__ b_in,
    const float* __restrict__ Wv,      // [384][128]
    const float* __restrict__ slot_mu,
    const float* __restrict__ Wih,     // [384][128]  (row j = gate output j)
    const float* __restrict__ Whh,     // [384][128]
    const float* __restrict__ b_ih, const float* __restrict__ b_hh,
    const float* __restrict__ gm, const float* __restrict__ bm,
    const float* __restrict__ W1,      // [128][256]
    const float* __restrict__ b1v,
    const float* __restrict__ W2,      // [256][128]
    const float* __restrict__ b2v,
    float* __restrict__ out_merged, float* __restrict__ out_mm,
    float* __restrict__ out_raw)
{
    __shared__ float S_l[384], u_l[128], h_l[128], m_l[128], hid_l[256];
    __shared__ float gx_l[384], gh_l[384];
    __shared__ float p2[2][384];
    __shared__ float p4[4][256];
    __shared__ float p8[8][128];
    __shared__ float red[4];
    int b = blockIdx.x, t = threadIdx.x;

    // --- A: colsum partials: 384 q x 2 chunk-halves (single 16-deep load chunk) ---
    if (t < 768) {
        int hc = t / 384, q = t % 384;
        float r[16];
#pragma unroll
        for (int i = 0; i < 16; i++)
            r[i] = G_part[((size_t)b * NCH + hc * 16 + i) * 384 + q];
        float s = 0.f;
#pragma unroll
        for (int i = 0; i < 16; i++) s += r[i];
        p2[hc][q] = s;
    }
    __syncthreads();
    if (t < 384) S_l[t] = g_in[t] * (p2[0][t] + p2[1][t]) + 4096.f * b_in[t];
    __syncthreads();

    // --- B: u partials: 128 d x 8 k-chunks (k=48 each) ---
    {
        int kc = t >> 7, d = t & 127;
        float s = 0.f;
#pragma unroll 1
        for (int kb = 0; kb < 48; kb += 16) {
            float w[16];
#pragma unroll
            for (int i = 0; i < 16; i++)
                w[i] = Wv[(size_t)(kc * 48 + kb + i) * 128 + d];
#pragma unroll
            for (int i = 0; i < 16; i++) s += S_l[kc * 48 + kb + i] * w[i];
        }
        p8[kc][d] = s;
    }
    __syncthreads();
    if (t < 128) {
        float s = 0.f;
#pragma unroll
        for (int kc = 0; kc < 8; kc++) s += p8[kc][t];
        u_l[t] = s * ATTN_NORM_C;
        h_l[t] = slot_mu[t];
    }
    __syncthreads();

    // --- C: gx partials: 384 j x 2 k-chunks (k=64 each); iteration-invariant ---
    // Direct row read: thread (kc,j) consumes Wih[j][kc*64 .. kc*64+64) = 16 aligned float4s.
    if (t < 768) {
        int kc = t / 384, j = t % 384;
        const float4* wr = (const float4*)(Wih + (size_t)j * 128 + kc * 64);
        float s = 0.f;
#pragma unroll 1
        for (int cb = 0; cb < 2; cb++) {
            float4 w4[8];
#pragma unroll
            for (int i = 0; i < 8; i++) w4[i] = wr[cb * 8 + i];
#pragma unroll
            for (int i = 0; i < 8; i++) {
                int k = kc * 64 + cb * 32 + i * 4;
                s += u_l[k] * w4[i].x;
                s += u_l[k + 1] * w4[i].y;
                s += u_l[k + 2] * w4[i].z;
                s += u_l[k + 3] * w4[i].w;
            }
        }
        p2[kc][j] = s;
    }
    __syncthreads();
    if (t < 384) gx_l[t] = b_ih[t] + p2[0][t] + p2[1][t];
    __syncthreads();

    float h = (t < 128) ? h_l[t] : 0.f;
    float hn = 0.f;
#pragma unroll 1
    for (int it = 0; it < 3; it++) {
        // --- D: gh partials: 384 j x 2 k-chunks (direct Whh row read) ---
        if (t < 768) {
            int kc = t / 384, j = t % 384;
            const float4* wr = (const float4*)(Whh + (size_t)j * 128 + kc * 64);
            float s = 0.f;
#pragma unroll 1
            for (int cb = 0; cb < 2; cb++) {
                float4 w4[8];
#pragma unroll
                for (int i = 0; i < 8; i++) w4[i] = wr[cb * 8 + i];
#pragma unroll
                for (int i = 0; i < 8; i++) {
                    int k = kc * 64 + cb * 32 + i * 4;
                    s += h_l[k] * w4[i].x;
                    s += h_l[k + 1] * w4[i].y;
                    s += h_l[k + 2] * w4[i].z;
                    s += h_l[k + 3] * w4[i].w;
                }
            }
            p2[kc][j] = s;
        }
        __syncthreads();
        if (t < 384) gh_l[t] = b_hh[t] + p2[0][t] + p2[1][t];
        __syncthreads();
        // --- E: gates + LN ---
        if (t < 128) {
            float r = 1.f / (1.f + expf(-(gx_l[t] + gh_l[t])));
            float z = 1.f / (1.f + expf(-(gx_l[128 + t] + gh_l[128 + t])));
            float nn = tanhf(gx_l[256 + t] + r * gh_l[256 + t]);
            hn = (1.f - z) * nn + z * h;
            float s = hn, sq = hn * hn;
#pragma unroll
            for (int m = 1; m < 64; m <<= 1) { s += __shfl_xor(s, m, 64); sq += __shfl_xor(sq, m, 64); }
            if ((t & 63) == 0) { red[(t >> 6) * 2] = s; red[(t >> 6) * 2 + 1] = sq; }
        }
        __syncthreads();
        if (t < 128) {
            float s = red[0] + red[2], sq = red[1] + red[3];
            float mean = s * (1.f / 128.f), var = sq * (1.f / 128.f) - mean * mean;
            float rstd = rsqrtf(var + LN_EPS);
            m_l[t] = (hn - mean) * rstd * gm[t] + bm[t];
        }
        __syncthreads();
        // --- F: mlp1 partials: 256 j x 4 k-chunks (k=32 each) ---
        {
            int kc = t >> 8, j = t & 255;
            float s = 0.f;
#pragma unroll 1
            for (int kb = 0; kb < 32; kb += 16) {
                float w[16];
#pragma unroll
                for (int i = 0; i < 16; i++)
                    w[i] = W1[(size_t)(kc * 32 + kb + i) * 256 + j];
#pragma unroll
                for (int i = 0; i < 16; i++) s += m_l[kc * 32 + kb + i] * w[i];
            }
            p4[kc][j] = s;
        }
        __syncthreads();
        if (t < 256) {
            float a = b1v[t] + ((p4[0][t] + p4[1][t]) + (p4[2][t] + p4[3][t]));
            hid_l[t] = a / (1.f + expf(-a));   // silu
        }
        __syncthreads();
        // --- G: mlp2 partials: 128 j x 8 k-chunks (k=32 each) ---
        {
            int kc = t >> 7, j = t & 127;
            float s = 0.f;
#pragma unroll 1
            for (int kb = 0; kb < 32; kb += 16) {
                float w[16];
#pragma unroll
                for (int i = 0; i < 16; i++)
                    w[i] = W2[(size_t)(kc * 32 + kb + i) * 128 + j];
#pragma unroll
                for (int i = 0; i < 16; i++) s += hid_l[kc * 32 + kb + i] * w[i];
            }
            p8[kc][j] = s;
        }
        __syncthreads();
        if (t < 128) {
            float s = 0.f;
#pragma unroll
            for (int kc = 0; kc < 8; kc++) s += p8[kc][t];
            h = hn + b2v[t] + s;
            h_l[t] = h;
        }
        __syncthreads();
    }

    // merge: all 8 slots identical; off-diag sim = cos(h,h)
    if (t < 128) {
        float s2 = h * h;
#pragma unroll
        for (int m = 1; m < 64; m <<= 1) s2 += __shfl_xor(s2, m, 64);
        if ((t & 63) == 0) red[t >> 6] = s2;
    }
    __syncthreads();
    if (t < 128) {
        float ss = red[0] + red[1];
        float nrm = fmaxf(sqrtf(ss), 1e-12f);
        float simv = ss / (nrm * nrm);
        int allmerge = (simv > THRESH) ? 1 : 0;
#pragma unroll
        for (int sl = 0; sl < 8; sl++) {
            out_raw[((size_t)(b * 8 + sl)) * 128 + t] = h;
            float mv = (sl == 0) ? h : (allmerge ? 0.f : h);
            out_merged[((size_t)(b * 8 + sl)) * 128 + t] = mv;
        }
        if (t < 8) out_mm[b * 8 + t] = allmerge ? 0.f : (float)t;
    }
}

extern "C" void kernel_launch(void* const* d_in, const int* in_sizes, int n_in,
                              void* d_out, int out_size, void* d_ws, size_t ws_size,
                              hipStream_t stream) {
    const float* feat    = (const float*)d_in[0];
    const float* ln_in_g = (const float*)d_in[1];
    const float* ln_in_b = (const float*)d_in[2];
    const float* Wv      = (const float*)d_in[4];
    const float* W_ih    = (const float*)d_in[8];
    const float* W_hh    = (const float*)d_in[9];
    const float* b_ih    = (const float*)d_in[10];
    const float* b_hh    = (const float*)d_in[11];
    const float* ln_m_g  = (const float*)d_in[12];
    const float* ln_m_b  = (const float*)d_in[13];
    const float* W1      = (const float*)d_in[14];
    const float* b1      = (const float*)d_in[15];
    const float* W2      = (const float*)d_in[16];
    const float* b2      = (const float*)d_in[17];
    const float* slot_mu = (const float*)d_in[18];

    float* out        = (float*)d_out;
    float* out_merged = out;                       // 32768
    float* out_attn   = out + 32768;               // 1048576
    float* out_mm     = out + 32768 + 1048576;     // 256
    float* out_raw    = out_mm + 256;              // 32768

    float* G_part = (float*)d_ws;                  // [32][32][384] = 1,572,864 B

    colsum_kernel<<<dim3(NCH, BATCH), 256, 0, stream>>>(feat, G_part, out_attn);
    slots_kernel<<<32, 1024, 0, stream>>>(G_part, ln_in_g, ln_in_b, Wv, slot_mu,
                                          W_ih, W_hh, b_ih, b_hh, ln_m_g, ln_m_b,
                                          W1, b1, W2, b2,
                                          out_merged, out_mm, out_raw);
}

// Round 2
// 351.820 us; speedup vs baseline: 1.0026x; 1.0026x over previous
//
#include <hip/hip_runtime.h>

#define NSL 8
#define DIN 384
#define DS 128
#define BATCH 32
#define NPOS 4096
#define LN_EPS 1e-5f
#define THRESH 0.9f
#define NCH 32          // feature chunks per batch (128 rows each)

// attn = 0.125 exactly (softmax of identical logits across slots);
// sum over N = 512.0 exactly; 512.0f + 1e-8f == 512.0f; 0.125/512 = 2^-12
#define ATTN_NORM_C 0.000244140625f

// ---------------- K1: streaming  Σ_rows rstd·(x−μ)  (per column) + attn fill ----------------
// BYTE-IDENTICAL to prior round (at its ~32 us HBM roofline).
__global__ __launch_bounds__(256) void colsum_kernel(const float* __restrict__ feat,
                                                     float* __restrict__ G_part,   // [32][NCH][384]
                                                     float* __restrict__ out_attn) {
    __shared__ float S_lds[16][384];   // 24 KB
    int t = threadIdx.x, w = t >> 6, lane = t & 63;
    int group = lane >> 4, gl = lane & 15;
    int b = blockIdx.y, ch = blockIdx.x;
    int row0 = ch * 128 + w * 32 + group;
    const float4* fbase = (const float4*)(feat + ((size_t)b * NPOS + row0) * DIN);

    float4 acc[6];
#pragma unroll
    for (int s = 0; s < 6; s++) { acc[s].x = 0.f; acc[s].y = 0.f; acc[s].z = 0.f; acc[s].w = 0.f; }

    float4 xA[6], xB[6];
#pragma unroll
    for (int s = 0; s < 6; s++) xA[s] = fbase[s * 16 + gl];

#pragma unroll
    for (int j = 0; j < 8; j++) {
        if (j < 7) {
            const float4* rp = fbase + (size_t)(j + 1) * 384;
#pragma unroll
            for (int s = 0; s < 6; s++) xB[s] = rp[s * 16 + gl];
        }
        float sm = 0.f, sq = 0.f;
#pragma unroll
        for (int s = 0; s < 6; s++) {
            sm += xA[s].x + xA[s].y + xA[s].z + xA[s].w;
            sq += xA[s].x * xA[s].x + xA[s].y * xA[s].y + xA[s].z * xA[s].z + xA[s].w * xA[s].w;
        }
#pragma unroll
        for (int m = 1; m < 16; m <<= 1) {
            sm += __shfl_xor(sm, m, 64);
            sq += __shfl_xor(sq, m, 64);
        }
        float mean = sm * (1.f / 384.f);
        float var = sq * (1.f / 384.f) - mean * mean;
        float rstd = rsqrtf(var + LN_EPS);
#pragma unroll
        for (int s = 0; s < 6; s++) {
            acc[s].x += (xA[s].x - mean) * rstd;
            acc[s].y += (xA[s].y - mean) * rstd;
            acc[s].z += (xA[s].z - mean) * rstd;
            acc[s].w += (xA[s].w - mean) * rstd;
        }
#pragma unroll
        for (int s = 0; s < 6; s++) xA[s] = xB[s];
    }
    int gr = w * 4 + group;
#pragma unroll
    for (int s = 0; s < 6; s++)
        *(float4*)&S_lds[gr][s * 64 + gl * 4] = acc[s];
    __syncthreads();
    for (int q = t; q < 384; q += 256) {
        float v = 0.f;
#pragma unroll
        for (int r = 0; r < 16; r++) v += S_lds[r][q];
        G_part[((size_t)b * NCH + ch) * 384 + q] = v;
    }
    int s8 = t >> 5, p = t & 31;
    size_t ao = ((size_t)(b * 8 + s8)) * NPOS + ch * 128;
    out_attn[ao + p] = 0.125f;
    out_attn[ao + 32 + p] = 0.125f;
    out_attn[ao + 64 + p] = 0.125f;
    out_attn[ao + 96 + p] = 0.125f;
}

// ---------------- K2: 1024-thread block, phased matvecs ----------------
// One block per batch. Phases C/D this round: half-wave-per-row scheme.
// Row j of Wih/Whh = 512 B = exactly 32 lanes x float4 -> each wave instruction
// reads 2 contiguous rows (1024 B, perfectly coalesced + vectorized), 12
// independent passes/thread (pipelined loads). Dot product completed by a
// 5-step shfl_xor butterfly inside each 32-lane half; bias folded into the
// lane-0 write. Removes the prep transpose kernel AND one barrier+combine
// per C/D phase. Reductions remain deterministic (same order every block).
__global__ __launch_bounds__(1024) void slots_kernel(
    const float* __restrict__ G_part,
    const float* __restrict__ g_in, const float* __restrict__ b_in,
    const float* __restrict__ Wv,      // [384][128]
    const float* __restrict__ slot_mu,
    const float* __restrict__ Wih,     // [384][128]  (row j = gate output j)
    const float* __restrict__ Whh,     // [384][128]
    const float* __restrict__ b_ih, const float* __restrict__ b_hh,
    const float* __restrict__ gm, const float* __restrict__ bm,
    const float* __restrict__ W1,      // [128][256]
    const float* __restrict__ b1v,
    const float* __restrict__ W2,      // [256][128]
    const float* __restrict__ b2v,
    float* __restrict__ out_merged, float* __restrict__ out_mm,
    float* __restrict__ out_raw)
{
    __shared__ float S_l[384], u_l[128], h_l[128], m_l[128], hid_l[256];
    __shared__ float gx_l[384], gh_l[384];
    __shared__ float p2[2][384];
    __shared__ float p4[4][256];
    __shared__ float p8[8][128];
    __shared__ float red[4];
    int b = blockIdx.x, t = threadIdx.x;
    int hw = t >> 5, l32 = t & 31;     // half-wave id (0..31), lane within half

    // --- A: colsum partials: 384 q x 2 chunk-halves (single 16-deep load chunk) ---
    if (t < 768) {
        int hc = t / 384, q = t % 384;
        float r[16];
#pragma unroll
        for (int i = 0; i < 16; i++)
            r[i] = G_part[((size_t)b * NCH + hc * 16 + i) * 384 + q];
        float s = 0.f;
#pragma unroll
        for (int i = 0; i < 16; i++) s += r[i];
        p2[hc][q] = s;
    }
    __syncthreads();
    if (t < 384) S_l[t] = g_in[t] * (p2[0][t] + p2[1][t]) + 4096.f * b_in[t];
    __syncthreads();

    // --- B: u partials: 128 d x 8 k-chunks (k=48 each) ---
    {
        int kc = t >> 7, d = t & 127;
        float s = 0.f;
#pragma unroll 1
        for (int kb = 0; kb < 48; kb += 16) {
            float w[16];
#pragma unroll
            for (int i = 0; i < 16; i++)
                w[i] = Wv[(size_t)(kc * 48 + kb + i) * 128 + d];
#pragma unroll
            for (int i = 0; i < 16; i++) s += S_l[kc * 48 + kb + i] * w[i];
        }
        p8[kc][d] = s;
    }
    __syncthreads();
    if (t < 128) {
        float s = 0.f;
#pragma unroll
        for (int kc = 0; kc < 8; kc++) s += p8[kc][t];
        u_l[t] = s * ATTN_NORM_C;
        h_l[t] = slot_mu[t];
    }
    __syncthreads();

    // --- C: gx = b_ih + Wih @ u  (iteration-invariant) ---
    // half-wave hw handles rows j = pass*32 + hw; lane l32 covers k = 4*l32..4*l32+3
    {
        float4 uv = *(const float4*)&u_l[l32 * 4];
#pragma unroll
        for (int pass = 0; pass < 12; pass++) {
            int j = pass * 32 + hw;
            float4 w4 = *(const float4*)(Wih + (size_t)j * 128 + l32 * 4);
            float s = uv.x * w4.x + uv.y * w4.y + uv.z * w4.z + uv.w * w4.w;
#pragma unroll
            for (int m = 1; m < 32; m <<= 1) s += __shfl_xor(s, m, 64);
            if (l32 == 0) gx_l[j] = b_ih[j] + s;
        }
    }
    __syncthreads();

    float h = (t < 128) ? h_l[t] : 0.f;
    float hn = 0.f;
#pragma unroll 1
    for (int it = 0; it < 3; it++) {
        // --- D: gh = b_hh + Whh @ h (half-wave-per-row, coalesced float4) ---
        {
            float4 hv = *(const float4*)&h_l[l32 * 4];
#pragma unroll
            for (int pass = 0; pass < 12; pass++) {
                int j = pass * 32 + hw;
                float4 w4 = *(const float4*)(Whh + (size_t)j * 128 + l32 * 4);
                float s = hv.x * w4.x + hv.y * w4.y + hv.z * w4.z + hv.w * w4.w;
#pragma unroll
                for (int m = 1; m < 32; m <<= 1) s += __shfl_xor(s, m, 64);
                if (l32 == 0) gh_l[j] = b_hh[j] + s;
            }
        }
        __syncthreads();
        // --- E: gates + LN ---
        if (t < 128) {
            float r = 1.f / (1.f + expf(-(gx_l[t] + gh_l[t])));
            float z = 1.f / (1.f + expf(-(gx_l[128 + t] + gh_l[128 + t])));
            float nn = tanhf(gx_l[256 + t] + r * gh_l[256 + t]);
            hn = (1.f - z) * nn + z * h;
            float s = hn, sq = hn * hn;
#pragma unroll
            for (int m = 1; m < 64; m <<= 1) { s += __shfl_xor(s, m, 64); sq += __shfl_xor(sq, m, 64); }
            if ((t & 63) == 0) { red[(t >> 6) * 2] = s; red[(t >> 6) * 2 + 1] = sq; }
        }
        __syncthreads();
        if (t < 128) {
            float s = red[0] + red[2], sq = red[1] + red[3];
            float mean = s * (1.f / 128.f), var = sq * (1.f / 128.f) - mean * mean;
            float rstd = rsqrtf(var + LN_EPS);
            m_l[t] = (hn - mean) * rstd * gm[t] + bm[t];
        }
        __syncthreads();
        // --- F: mlp1 partials: 256 j x 4 k-chunks (k=32 each) ---
        {
            int kc = t >> 8, j = t & 255;
            float s = 0.f;
#pragma unroll 1
            for (int kb = 0; kb < 32; kb += 16) {
                float w[16];
#pragma unroll
                for (int i = 0; i < 16; i++)
                    w[i] = W1[(size_t)(kc * 32 + kb + i) * 256 + j];
#pragma unroll
                for (int i = 0; i < 16; i++) s += m_l[kc * 32 + kb + i] * w[i];
            }
            p4[kc][j] = s;
        }
        __syncthreads();
        if (t < 256) {
            float a = b1v[t] + ((p4[0][t] + p4[1][t]) + (p4[2][t] + p4[3][t]));
            hid_l[t] = a / (1.f + expf(-a));   // silu
        }
        __syncthreads();
        // --- G: mlp2 partials: 128 j x 8 k-chunks (k=32 each) ---
        {
            int kc = t >> 7, j = t & 127;
            float s = 0.f;
#pragma unroll 1
            for (int kb = 0; kb < 32; kb += 16) {
                float w[16];
#pragma unroll
                for (int i = 0; i < 16; i++)
                    w[i] = W2[(size_t)(kc * 32 + kb + i) * 128 + j];
#pragma unroll
                for (int i = 0; i < 16; i++) s += hid_l[kc * 32 + kb + i] * w[i];
            }
            p8[kc][j] = s;
        }
        __syncthreads();
        if (t < 128) {
            float s = 0.f;
#pragma unroll
            for (int kc = 0; kc < 8; kc++) s += p8[kc][t];
            h = hn + b2v[t] + s;
            h_l[t] = h;
        }
        __syncthreads();
    }

    // merge: all 8 slots identical; off-diag sim = cos(h,h)
    if (t < 128) {
        float s2 = h * h;
#pragma unroll
        for (int m = 1; m < 64; m <<= 1) s2 += __shfl_xor(s2, m, 64);
        if ((t & 63) == 0) red[t >> 6] = s2;
    }
    __syncthreads();
    if (t < 128) {
        float ss = red[0] + red[1];
        float nrm = fmaxf(sqrtf(ss), 1e-12f);
        float simv = ss / (nrm * nrm);
        int allmerge = (simv > THRESH) ? 1 : 0;
#pragma unroll
        for (int sl = 0; sl < 8; sl++) {
            out_raw[((size_t)(b * 8 + sl)) * 128 + t] = h;
            float mv = (sl == 0) ? h : (allmerge ? 0.f : h);
            out_merged[((size_t)(b * 8 + sl)) * 128 + t] = mv;
        }
        if (t < 8) out_mm[b * 8 + t] = allmerge ? 0.f : (float)t;
    }
}

extern "C" void kernel_launch(void* const* d_in, const int* in_sizes, int n_in,
                              void* d_out, int out_size, void* d_ws, size_t ws_size,
                              hipStream_t stream) {
    const float* feat    = (const float*)d_in[0];
    const float* ln_in_g = (const float*)d_in[1];
    const float* ln_in_b = (const float*)d_in[2];
    const float* Wv      = (const float*)d_in[4];
    const float* W_ih    = (const float*)d_in[8];
    const float* W_hh    = (const float*)d_in[9];
    const float* b_ih    = (const float*)d_in[10];
    const float* b_hh    = (const float*)d_in[11];
    const float* ln_m_g  = (const float*)d_in[12];
    const float* ln_m_b  = (const float*)d_in[13];
    const float* W1      = (const float*)d_in[14];
    const float* b1      = (const float*)d_in[15];
    const float* W2      = (const float*)d_in[16];
    const float* b2      = (const float*)d_in[17];
    const float* slot_mu = (const float*)d_in[18];

    float* out        = (float*)d_out;
    float* out_merged = out;                       // 32768
    float* out_attn   = out + 32768;               // 1048576
    float* out_mm     = out + 32768 + 1048576;     // 256
    float* out_raw    = out_mm + 256;              // 32768

    float* G_part = (float*)d_ws;                  // [32][32][384] = 1,572,864 B

    colsum_kernel<<<dim3(NCH, BATCH), 256, 0, stream>>>(feat, G_part, out_attn);
    slots_kernel<<<32, 1024, 0, stream>>>(G_part, ln_in_g, ln_in_b, Wv, slot_mu,
                                          W_ih, W_hh, b_ih, b_hh, ln_m_g, ln_m_b,
                                          W1, b1, W2, b2,
                                          out_merged, out_mm, out_raw);
}

// Round 4
// 339.023 us; speedup vs baseline: 1.0404x; 1.0377x over previous
//
#include <hip/hip_runtime.h>

#define NSL 8
#define DIN 384
#define DS 128
#define BATCH 32
#define NPOS 4096
#define LN_EPS 1e-5f
#define THRESH 0.9f
#define NCH 32          // feature chunks per batch (128 rows each)

// attn = 0.125 exactly (softmax of identical logits across slots);
// sum over N = 512.0 exactly; 512.0f + 1e-8f == 512.0f; 0.125/512 = 2^-12
#define ATTN_NORM_C 0.000244140625f

// ---------------- K1: streaming  Σ_rows rstd·(x−μ)  (per column) + attn fill ----------------
// Main body BYTE-IDENTICAL to prior rounds (at its ~32 us HBM roofline).
// Tail folds the W_ih/W_hh transpose (formerly prep_kernel) into the
// ch==0 / ch==1 blocks — 12 loads+stores per thread on 64 of 1024 blocks,
// hidden under the 201 MB feature stream. Saves one dispatch.
__global__ __launch_bounds__(256) void colsum_kernel(const float* __restrict__ feat,
                                                     const float* __restrict__ Wih,
                                                     const float* __restrict__ Whh,
                                                     float* __restrict__ WihT,
                                                     float* __restrict__ WhhT,
                                                     float* __restrict__ G_part,   // [32][NCH][384]
                                                     float* __restrict__ out_attn) {
    __shared__ float S_lds[16][384];   // 24 KB
    int t = threadIdx.x, w = t >> 6, lane = t & 63;
    int group = lane >> 4, gl = lane & 15;
    int b = blockIdx.y, ch = blockIdx.x;
    int row0 = ch * 128 + w * 32 + group;
    const float4* fbase = (const float4*)(feat + ((size_t)b * NPOS + row0) * DIN);

    float4 acc[6];
#pragma unroll
    for (int s = 0; s < 6; s++) { acc[s].x = 0.f; acc[s].y = 0.f; acc[s].z = 0.f; acc[s].w = 0.f; }

    float4 xA[6], xB[6];
#pragma unroll
    for (int s = 0; s < 6; s++) xA[s] = fbase[s * 16 + gl];

#pragma unroll
    for (int j = 0; j < 8; j++) {
        if (j < 7) {
            const float4* rp = fbase + (size_t)(j + 1) * 384;
#pragma unroll
            for (int s = 0; s < 6; s++) xB[s] = rp[s * 16 + gl];
        }
        float sm = 0.f, sq = 0.f;
#pragma unroll
        for (int s = 0; s < 6; s++) {
            sm += xA[s].x + xA[s].y + xA[s].z + xA[s].w;
            sq += xA[s].x * xA[s].x + xA[s].y * xA[s].y + xA[s].z * xA[s].z + xA[s].w * xA[s].w;
        }
#pragma unroll
        for (int m = 1; m < 16; m <<= 1) {
            sm += __shfl_xor(sm, m, 64);
            sq += __shfl_xor(sq, m, 64);
        }
        float mean = sm * (1.f / 384.f);
        float var = sq * (1.f / 384.f) - mean * mean;
        float rstd = rsqrtf(var + LN_EPS);
#pragma unroll
        for (int s = 0; s < 6; s++) {
            acc[s].x += (xA[s].x - mean) * rstd;
            acc[s].y += (xA[s].y - mean) * rstd;
            acc[s].z += (xA[s].z - mean) * rstd;
            acc[s].w += (xA[s].w - mean) * rstd;
        }
#pragma unroll
        for (int s = 0; s < 6; s++) xA[s] = xB[s];
    }
    int gr = w * 4 + group;
#pragma unroll
    for (int s = 0; s < 6; s++)
        *(float4*)&S_lds[gr][s * 64 + gl * 4] = acc[s];
    __syncthreads();
    for (int q = t; q < 384; q += 256) {
        float v = 0.f;
#pragma unroll
        for (int r = 0; r < 16; r++) v += S_lds[r][q];
        G_part[((size_t)b * NCH + ch) * 384 + q] = v;
    }
    int s8 = t >> 5, p = t & 31;
    size_t ao = ((size_t)(b * 8 + s8)) * NPOS + ch * 128;
    out_attn[ao + p] = 0.125f;
    out_attn[ao + 32 + p] = 0.125f;
    out_attn[ao + 64 + p] = 0.125f;
    out_attn[ao + 96 + p] = 0.125f;

    // --- folded prep: transpose W_ih / W_hh -> [128][384] ---
    if (ch < 2) {
        const float* Wsrc = (ch == 0) ? Wih : Whh;
        float* Wdst = (ch == 0) ? WihT : WhhT;
        int gid = b * 256 + t;           // 0..8191
#pragma unroll
        for (int e = 0; e < 6; e++) {
            int idx = e * 8192 + gid;    // coalesced read
            int j = idx >> 7, k = idx & 127;
            Wdst[k * 384 + j] = Wsrc[idx];
        }
    }
}

// ---------------- K2: 1024-thread block, phased matvecs ----------------
// One block per batch. C/D: transposed k-major weights (round-0's proven-best
// layout) read as float4-in-j — thread (kc,jq) loads 16 float4s of
// WihT[k][4jq..4jq+3] in 2 chunks (2 latency stalls vs round-0's 4, 4x fewer
// load insts, perfectly coalesced 1024 B / wave-inst, zero shuffles).
// Combine: 8-deep LDS partial sum, ascending kc — deterministic.
__global__ __launch_bounds__(1024) void slots_kernel(
    const float* __restrict__ G_part,
    const float* __restrict__ g_in, const float* __restrict__ b_in,
    const float* __restrict__ Wv,      // [384][128]
    const float* __restrict__ slot_mu,
    const float* __restrict__ WihT,    // [128][384] k-major
    const float* __restrict__ WhhT,    // [128][384]
    const float* __restrict__ b_ih, const float* __restrict__ b_hh,
    const float* __restrict__ gm, const float* __restrict__ bm,
    const float* __restrict__ W1,      // [128][256]
    const float* __restrict__ b1v,
    const float* __restrict__ W2,      // [256][128]
    const float* __restrict__ b2v,
    float* __restrict__ out_merged, float* __restrict__ out_mm,
    float* __restrict__ out_raw)
{
    __shared__ float S_l[384], u_l[128], h_l[128], m_l[128], hid_l[256];
    __shared__ float gx_l[384], gh_l[384];
    __shared__ float p2[2][384];
    __shared__ float p4[4][256];
    __shared__ float p8[8][128];
    __shared__ float p8w[8][384];      // 12 KB: C/D partials
    __shared__ float red[4];
    int b = blockIdx.x, t = threadIdx.x;

    // --- A: colsum partials: 384 q x 2 chunk-halves (single 16-deep load chunk) ---
    if (t < 768) {
        int hc = t / 384, q = t % 384;
        float r[16];
#pragma unroll
        for (int i = 0; i < 16; i++)
            r[i] = G_part[((size_t)b * NCH + hc * 16 + i) * 384 + q];
        float s = 0.f;
#pragma unroll
        for (int i = 0; i < 16; i++) s += r[i];
        p2[hc][q] = s;
    }
    __syncthreads();
    if (t < 384) S_l[t] = g_in[t] * (p2[0][t] + p2[1][t]) + 4096.f * b_in[t];
    __syncthreads();

    // --- B: u partials: 128 d x 8 k-chunks (k=48 each) ---
    {
        int kc = t >> 7, d = t & 127;
        float s = 0.f;
#pragma unroll 1
        for (int kb = 0; kb < 48; kb += 16) {
            float w[16];
#pragma unroll
            for (int i = 0; i < 16; i++)
                w[i] = Wv[(size_t)(kc * 48 + kb + i) * 128 + d];
#pragma unroll
            for (int i = 0; i < 16; i++) s += S_l[kc * 48 + kb + i] * w[i];
        }
        p8[kc][d] = s;
    }
    __syncthreads();
    if (t < 128) {
        float s = 0.f;
#pragma unroll
        for (int kc = 0; kc < 8; kc++) s += p8[kc][t];
        u_l[t] = s * ATTN_NORM_C;
        h_l[t] = slot_mu[t];
    }
    __syncthreads();

    // --- C: gx partials: 8 kc x 96 jq, float4-in-j from WihT (iteration-invariant) ---
    if (t < 768) {
        int kc = t / 96, jq = t % 96;
        const float4* wp = (const float4*)WihT;   // [128][96] float4
        float4 s4 = {0.f, 0.f, 0.f, 0.f};
#pragma unroll 1
        for (int cb = 0; cb < 2; cb++) {
            float4 w4[8];
#pragma unroll
            for (int i = 0; i < 8; i++)
                w4[i] = wp[(size_t)(kc * 16 + cb * 8 + i) * 96 + jq];
#pragma unroll
            for (int i = 0; i < 8; i++) {
                float uk = u_l[kc * 16 + cb * 8 + i];
                s4.x += uk * w4[i].x; s4.y += uk * w4[i].y;
                s4.z += uk * w4[i].z; s4.w += uk * w4[i].w;
            }
        }
        *(float4*)&p8w[kc][jq * 4] = s4;
    }
    __syncthreads();
    if (t < 384) {
        float s = 0.f;
#pragma unroll
        for (int kc = 0; kc < 8; kc++) s += p8w[kc][t];
        gx_l[t] = b_ih[t] + s;
    }
    __syncthreads();

    float h = (t < 128) ? h_l[t] : 0.f;
    float hn = 0.f;
#pragma unroll 1
    for (int it = 0; it < 3; it++) {
        // --- D: gh partials: 8 kc x 96 jq, float4-in-j from WhhT ---
        if (t < 768) {
            int kc = t / 96, jq = t % 96;
            const float4* wp = (const float4*)WhhT;
            float4 s4 = {0.f, 0.f, 0.f, 0.f};
#pragma unroll 1
            for (int cb = 0; cb < 2; cb++) {
                float4 w4[8];
#pragma unroll
                for (int i = 0; i < 8; i++)
                    w4[i] = wp[(size_t)(kc * 16 + cb * 8 + i) * 96 + jq];
#pragma unroll
                for (int i = 0; i < 8; i++) {
                    float hk = h_l[kc * 16 + cb * 8 + i];
                    s4.x += hk * w4[i].x; s4.y += hk * w4[i].y;
                    s4.z += hk * w4[i].z; s4.w += hk * w4[i].w;
                }
            }
            *(float4*)&p8w[kc][jq * 4] = s4;
        }
        __syncthreads();
        if (t < 384) {
            float s = 0.f;
#pragma unroll
            for (int kc = 0; kc < 8; kc++) s += p8w[kc][t];
            gh_l[t] = b_hh[t] + s;
        }
        __syncthreads();
        // --- E: gates + LN ---
        if (t < 128) {
            float r = 1.f / (1.f + expf(-(gx_l[t] + gh_l[t])));
            float z = 1.f / (1.f + expf(-(gx_l[128 + t] + gh_l[128 + t])));
            float nn = tanhf(gx_l[256 + t] + r * gh_l[256 + t]);
            hn = (1.f - z) * nn + z * h;
            float s = hn, sq = hn * hn;
#pragma unroll
            for (int m = 1; m < 64; m <<= 1) { s += __shfl_xor(s, m, 64); sq += __shfl_xor(sq, m, 64); }
            if ((t & 63) == 0) { red[(t >> 6) * 2] = s; red[(t >> 6) * 2 + 1] = sq; }
        }
        __syncthreads();
        if (t < 128) {
            float s = red[0] + red[2], sq = red[1] + red[3];
            float mean = s * (1.f / 128.f), var = sq * (1.f / 128.f) - mean * mean;
            float rstd = rsqrtf(var + LN_EPS);
            m_l[t] = (hn - mean) * rstd * gm[t] + bm[t];
        }
        __syncthreads();
        // --- F: mlp1 partials: 256 j x 4 k-chunks (k=32 each) ---
        {
            int kc = t >> 8, j = t & 255;
            float s = 0.f;
#pragma unroll 1
            for (int kb = 0; kb < 32; kb += 16) {
                float w[16];
#pragma unroll
                for (int i = 0; i < 16; i++)
                    w[i] = W1[(size_t)(kc * 32 + kb + i) * 256 + j];
#pragma unroll
                for (int i = 0; i < 16; i++) s += m_l[kc * 32 + kb + i] * w[i];
            }
            p4[kc][j] = s;
        }
        __syncthreads();
        if (t < 256) {
            float a = b1v[t] + ((p4[0][t] + p4[1][t]) + (p4[2][t] + p4[3][t]));
            hid_l[t] = a / (1.f + expf(-a));   // silu
        }
        __syncthreads();
        // --- G: mlp2 partials: 128 j x 8 k-chunks (k=32 each) ---
        {
            int kc = t >> 7, j = t & 127;
            float s = 0.f;
#pragma unroll 1
            for (int kb = 0; kb < 32; kb += 16) {
                float w[16];
#pragma unroll
                for (int i = 0; i < 16; i++)
                    w[i] = W2[(size_t)(kc * 32 + kb + i) * 128 + j];
#pragma unroll
                for (int i = 0; i < 16; i++) s += hid_l[kc * 32 + kb + i] * w[i];
            }
            p8[kc][j] = s;
        }
        __syncthreads();
        if (t < 128) {
            float s = 0.f;
#pragma unroll
            for (int kc = 0; kc < 8; kc++) s += p8[kc][t];
            h = hn + b2v[t] + s;
            h_l[t] = h;
        }
        __syncthreads();
    }

    // merge: all 8 slots identical; off-diag sim = cos(h,h)
    if (t < 128) {
        float s2 = h * h;
#pragma unroll
        for (int m = 1; m < 64; m <<= 1) s2 += __shfl_xor(s2, m, 64);
        if ((t & 63) == 0) red[t >> 6] = s2;
    }
    __syncthreads();
    if (t < 128) {
        float ss = red[0] + red[1];
        float nrm = fmaxf(sqrtf(ss), 1e-12f);
        float simv = ss / (nrm * nrm);
        int allmerge = (simv > THRESH) ? 1 : 0;
#pragma unroll
        for (int sl = 0; sl < 8; sl++) {
            out_raw[((size_t)(b * 8 + sl)) * 128 + t] = h;
            float mv = (sl == 0) ? h : (allmerge ? 0.f : h);
            out_merged[((size_t)(b * 8 + sl)) * 128 + t] = mv;
        }
        if (t < 8) out_mm[b * 8 + t] = allmerge ? 0.f : (float)t;
    }
}

extern "C" void kernel_launch(void* const* d_in, const int* in_sizes, int n_in,
                              void* d_out, int out_size, void* d_ws, size_t ws_size,
                              hipStream_t stream) {
    const float* feat    = (const float*)d_in[0];
    const float* ln_in_g = (const float*)d_in[1];
    const float* ln_in_b = (const float*)d_in[2];
    const float* Wv      = (const float*)d_in[4];
    const float* W_ih    = (const float*)d_in[8];
    const float* W_hh    = (const float*)d_in[9];
    const float* b_ih    = (const float*)d_in[10];
    const float* b_hh    = (const float*)d_in[11];
    const float* ln_m_g  = (const float*)d_in[12];
    const float* ln_m_b  = (const float*)d_in[13];
    const float* W1      = (const float*)d_in[14];
    const float* b1      = (const float*)d_in[15];
    const float* W2      = (const float*)d_in[16];
    const float* b2      = (const float*)d_in[17];
    const float* slot_mu = (const float*)d_in[18];

    float* out        = (float*)d_out;
    float* out_merged = out;                       // 32768
    float* out_attn   = out + 32768;               // 1048576
    float* out_mm     = out + 32768 + 1048576;     // 256
    float* out_raw    = out_mm + 256;              // 32768

    float* G_part = (float*)d_ws;                  // [32][32][384] = 1,572,864 B
    float* WihT   = G_part + 32 * NCH * 384;       // [128][384] = 196,608 B
    float* WhhT   = WihT + 49152;                  // [128][384] = 196,608 B

    colsum_kernel<<<dim3(NCH, BATCH), 256, 0, stream>>>(feat, W_ih, W_hh, WihT, WhhT,
                                                        G_part, out_attn);
    slots_kernel<<<32, 1024, 0, stream>>>(G_part, ln_in_g, ln_in_b, Wv, slot_mu,
                                          WihT, WhhT, b_ih, b_hh, ln_m_g, ln_m_b,
                                          W1, b1, W2, b2,
                                          out_merged, out_mm, out_raw);
}